// Round 3
// baseline (932.324 us; speedup 1.0000x reference)
//
#include <hip/hip_runtime.h>
#include <hip/hip_bf16.h>

// EfficientLinearAttention on MI355X (gfx950).
// B=8 T=8192 C=512 H=8 D=64.  M = B*T = 65536 rows.
//
// R2 post-mortem: two all-NaN rounds with no NaN mechanism under bf16 inputs
// -> leading theory: external tensors are fp32 (reference is jnp.float32) and
// reading them as bf16 decodes mantissa garbage as NaN/Inf.  This build
// probes the dtype ON DEVICE (dtype_probe -> flag in ws) and every GEMM
// switches its external load/store paths on the flag (wave-uniform branch).
// Internal tensors (Q/K/V/attn/KVb) are always bf16; kv_reduce / kv_pack /
// attn_apply are unchanged from R2 (exhaustively re-audited: fragment maps,
// alignment, bank math, coverage all check out).
//
// Pipeline:
//   memset KV/Ksum/flag, dtype_probe
//   gemm_nt<ELU1,AEXT>      : Q = elu(x@Wq^T+bq)+1   -> ws.Q  bf16
//   gemm_nt<ELU1,AEXT>      : K = elu(x@Wk^T+bk)+1   -> ws.K  bf16
//   gemm_nt<AEXT>           : V = x@Wv^T+bv          -> d_out scratch, bf16
//   kv_reduce               : KV += K^T V (MFMA, 8 T-chunks, fp32 atomics)
//   kv_pack                 : KV fp32 -> bf16 in MFMA B-fragment order
//   attn_apply              : attn = (Q@KV)/(Q.Ksum+1e-6), in-place on ws.Q
//   gemm_nt<CEXT>           : out = attn@Wo^T+bo     -> d_out (dtype per flag)

typedef unsigned short u16t;
typedef unsigned int   u32t;
typedef __bf16 v8bf __attribute__((ext_vector_type(8)));
typedef u16t   v8u  __attribute__((ext_vector_type(8)));
typedef float  v4f  __attribute__((ext_vector_type(4)));

static __device__ __forceinline__ float bf2f(u16t b) {
    u32t u = ((u32t)b) << 16;
    return __builtin_bit_cast(float, u);
}
static __device__ __forceinline__ u16t f2bf(float f) {
    u32t u = __builtin_bit_cast(u32t, f);
    u += 0x7fffu + ((u >> 16) & 1u);   // round-to-nearest-even
    return (u16t)(u >> 16);
}

// ---------------------------------------------------------------------------
// Detect external dtype.  bf16 x ~ N(0,1): no element has |v| >= 128
// (exponent field >= 134).  fp32 x read as u16 pairs: the low halves carry
// mantissa bits in the exponent field (~uniform) -> ~47% of 4096 hit.
// flag > 100  <=>  external tensors are fp32.
// ---------------------------------------------------------------------------
__global__ __launch_bounds__(256) void dtype_probe(
        const u16t* __restrict__ x, int* __restrict__ flag) {
    int cnt = 0;
    for (int i = threadIdx.x; i < 8192; i += 256) {
        const u32t e = ((u32t)x[i] >> 7) & 0xFFu;
        if (e >= 134u) ++cnt;
    }
    if (cnt) atomicAdd(flag, cnt);
}

// Stage 8 contiguous elements (16B of bf16) into LDS, converting from fp32
// (two float4 loads) when f32 is set.  off is in elements.
static __device__ __forceinline__ void stage8(
        u16t* dst, const u16t* p16, const float* p32, size_t off, bool f32) {
    if (f32) {
        const float4 a = *(const float4*)&p32[off];
        const float4 b = *(const float4*)&p32[off + 4];
        v8u r;
        r[0] = f2bf(a.x); r[1] = f2bf(a.y); r[2] = f2bf(a.z); r[3] = f2bf(a.w);
        r[4] = f2bf(b.x); r[5] = f2bf(b.y); r[6] = f2bf(b.z); r[7] = f2bf(b.w);
        *(v8u*)dst = r;
    } else {
        *(uint4*)dst = *(const uint4*)&p16[off];
    }
}

// ---------------------------------------------------------------------------
// C[M,N] = act(A[M,K] @ B[N,K]^T + bias[N]), fp32 accum.
// grid = (M/128, N/128), block = 256 (4 waves, 2x2 wave grid, 64x64/wave,
// 4x4 MFMA 16x16x32 tiles).  LDS stride 32 u16 = 64 B: b128-aligned,
// conflict-free (8 lanes per 4-bank window = wave64 floor).
// AEXT: A is an external tensor (dtype per flag); else internal bf16.
// CEXT: C is d_out (dtype per flag); else internal bf16.
// B/bias always external.
// ---------------------------------------------------------------------------
template<bool ELU1, bool AEXT, bool CEXT>
__global__ __launch_bounds__(256) void gemm_nt(
        const u16t* __restrict__ A16, const float* __restrict__ A32,
        const u16t* __restrict__ B16, const float* __restrict__ B32,
        const u16t* __restrict__ bias16, const float* __restrict__ bias32,
        u16t* __restrict__ C16, float* __restrict__ C32,
        const int* __restrict__ flag, int Kd, int N) {
    __shared__ u16t As[128][32];
    __shared__ u16t Bs[128][32];
    const bool f32 = (*flag > 100);
    const int tid  = threadIdx.x;
    const int w    = tid >> 6;
    const int lane = tid & 63;
    const int quad = lane >> 4;
    const int l16  = lane & 15;
    const int wm   = (w & 1) * 64;
    const int wn   = (w >> 1) * 64;
    const size_t mbase = (size_t)blockIdx.x * 128;
    const size_t nbase = (size_t)blockIdx.y * 128;

    v4f acc[4][4];
#pragma unroll
    for (int i = 0; i < 4; ++i)
#pragma unroll
        for (int j = 0; j < 4; ++j) acc[i][j] = (v4f){0.f, 0.f, 0.f, 0.f};

    const int srow = tid >> 2;          // 0..63
    const int sc8  = (tid & 3) * 8;     // 0,8,16,24

    for (int kt = 0; kt < Kd; kt += 32) {
#pragma unroll
        for (int i = 0; i < 2; ++i) {
            const int row = srow + i * 64;
            stage8(&As[row][sc8], A16, A32,
                   (mbase + row) * (size_t)Kd + kt + sc8, AEXT && f32);
            stage8(&Bs[row][sc8], B16, B32,
                   (nbase + row) * (size_t)Kd + kt + sc8, f32);
        }
        __syncthreads();

        v8bf af[4], bfr[4];
#pragma unroll
        for (int mi = 0; mi < 4; ++mi)
            af[mi] = *(const v8bf*)&As[wm + mi * 16 + l16][quad * 8];
#pragma unroll
        for (int ni = 0; ni < 4; ++ni)
            bfr[ni] = *(const v8bf*)&Bs[wn + ni * 16 + l16][quad * 8];
#pragma unroll
        for (int mi = 0; mi < 4; ++mi)
#pragma unroll
            for (int ni = 0; ni < 4; ++ni)
                acc[mi][ni] = __builtin_amdgcn_mfma_f32_16x16x32_bf16(
                    af[mi], bfr[ni], acc[mi][ni], 0, 0, 0);
        __syncthreads();
    }

#pragma unroll
    for (int ni = 0; ni < 4; ++ni) {
        const int col = (int)nbase + wn + ni * 16 + l16;
        const float bb = f32 ? bias32[col] : bf2f(bias16[col]);
#pragma unroll
        for (int mi = 0; mi < 4; ++mi) {
#pragma unroll
            for (int r = 0; r < 4; ++r) {
                const size_t row = mbase + wm + mi * 16 + quad * 4 + r;
                float v = acc[mi][ni][r] + bb;
                if (ELU1) v = (v > 0.f) ? (v + 1.f) : __expf(v);  // elu(x)+1
                if (CEXT && f32) C32[row * (size_t)N + col] = v;
                else             C16[row * (size_t)N + col] = f2bf(v);
            }
        }
    }
}

// ---------------------------------------------------------------------------
// KV[bh][d][e] = sum_t K[t][d]*V[t][e];  Ksum[bh][d] = sum_t K[t][d].
// grid = (64 bh, 8 T-chunks of 1024), block = 256.  64-t tiles staged in LDS
// [t][d] (stride 66 u16 = 132B, u32-aligned writes; scalar u16 gathers are
// conflict-free: bank = (8q+j) + 8*tile + l16/2 covers all 32).  MFMA A=K^T,
// B=V; wave w owns d-tile w.  fp32 atomicAdd merges chunks.
// ---------------------------------------------------------------------------
__global__ __launch_bounds__(256) void kv_reduce(
        const u16t* __restrict__ Kp, const u16t* __restrict__ Vp,
        float* __restrict__ KV, float* __restrict__ Ksum) {
    __shared__ u16t Kl[64][66];
    __shared__ u16t Vl[64][66];
    const int bh = blockIdx.x;
    const int chunk = blockIdx.y;
    const int b = bh >> 3, h = bh & 7;
    const int tid = threadIdx.x;
    const int w = tid >> 6, lane = tid & 63, quad = lane >> 4, l16 = lane & 15;
    const int trow0 = tid >> 3;         // 0..31
    const int c8 = (tid & 7) * 8;       // fixed 8 d-columns per thread
    const size_t rowbase = (size_t)b * 8192;

    v4f acc[4];
#pragma unroll
    for (int i = 0; i < 4; ++i) acc[i] = (v4f){0.f, 0.f, 0.f, 0.f};
    float ks[8];
#pragma unroll
    for (int j = 0; j < 8; ++j) ks[j] = 0.f;

    for (int tile = 0; tile < 16; ++tile) {
        const int t0 = chunk * 1024 + tile * 64;
#pragma unroll
        for (int i = 0; i < 2; ++i) {
            const int trow = trow0 + i * 32;
            const size_t goff = (rowbase + t0 + trow) * 512 + h * 64 + c8;
            const uint4 kq = *(const uint4*)&Kp[goff];
            const uint4 vq = *(const uint4*)&Vp[goff];
            *(u32t*)&Kl[trow][c8 + 0] = kq.x;
            *(u32t*)&Kl[trow][c8 + 2] = kq.y;
            *(u32t*)&Kl[trow][c8 + 4] = kq.z;
            *(u32t*)&Kl[trow][c8 + 6] = kq.w;
            *(u32t*)&Vl[trow][c8 + 0] = vq.x;
            *(u32t*)&Vl[trow][c8 + 2] = vq.y;
            *(u32t*)&Vl[trow][c8 + 4] = vq.z;
            *(u32t*)&Vl[trow][c8 + 6] = vq.w;
            const v8u ku = __builtin_bit_cast(v8u, kq);
#pragma unroll
            for (int j = 0; j < 8; ++j) ks[j] += bf2f(ku[j]);
        }
        __syncthreads();
#pragma unroll
        for (int ts = 0; ts < 2; ++ts) {
            v8u au;
#pragma unroll
            for (int j = 0; j < 8; ++j)
                au[j] = Kl[ts * 32 + quad * 8 + j][w * 16 + l16];
            const v8bf af = __builtin_bit_cast(v8bf, au);
#pragma unroll
            for (int et = 0; et < 4; ++et) {
                v8u bu;
#pragma unroll
                for (int j = 0; j < 8; ++j)
                    bu[j] = Vl[ts * 32 + quad * 8 + j][et * 16 + l16];
                acc[et] = __builtin_amdgcn_mfma_f32_16x16x32_bf16(
                    af, __builtin_bit_cast(v8bf, bu), acc[et], 0, 0, 0);
            }
        }
        __syncthreads();
    }

#pragma unroll
    for (int et = 0; et < 4; ++et)
#pragma unroll
        for (int r = 0; r < 4; ++r) {
            const int d = w * 16 + quad * 4 + r;
            const int e = et * 16 + l16;
            atomicAdd(&KV[((size_t)bh * 64 + d) * 64 + e], acc[et][r]);
        }
#pragma unroll
    for (int j = 0; j < 8; ++j)
        atomicAdd(&Ksum[bh * 64 + c8 + j], ks[j]);
}

// ---------------------------------------------------------------------------
// fp32 KV[bh][64][64] -> bf16 in MFMA B-fragment order:
// KVb[(bh*512 + ks*256 + nb*64 + lane)*8 + j] = KV[ks*32+quad*8+j][nb*16+l16]
// ---------------------------------------------------------------------------
__global__ __launch_bounds__(256) void kv_pack(
        const float* __restrict__ KV, u16t* __restrict__ KVb) {
    const int bh = blockIdx.x;
    const int tid = threadIdx.x;
#pragma unroll
    for (int i = 0; i < 2; ++i) {
        const int c = tid + i * 256;    // 0..511
        const int ksi = c >> 8;
        const int nb = (c >> 6) & 3;
        const int L = c & 63;
        const int quad = L >> 4, l16 = L & 15;
        v8u pk;
#pragma unroll
        for (int j = 0; j < 8; ++j) {
            const int d = ksi * 32 + quad * 8 + j;
            const int e = nb * 16 + l16;
            pk[j] = f2bf(KV[((size_t)bh * 64 + d) * 64 + e]);
        }
        *(v8u*)&KVb[((size_t)bh * 512 + c) * 8] = pk;
    }
}

// ---------------------------------------------------------------------------
// attn[t][h*64+e] = (sum_d Q[t][h*64+d]*KV[d][e]) / (Q[t]·Ksum + 1e-6)
// grid = (512 t-tiles of 128, 8 heads), block = 256.  In-place over Q (each
// block reads exactly the region it writes; all reads precede writes).
// Qs stride 72 u16 = 144 B: b128-aligned, conflict-free.
// ---------------------------------------------------------------------------
__global__ __launch_bounds__(256) void attn_apply(
        u16t* __restrict__ Q, const u16t* __restrict__ KVb,
        const float* __restrict__ Ksum) {
    __shared__ u16t Qs[128][72];
    __shared__ float ksl[64];
    __shared__ float rden[128];
    const int bx = blockIdx.x;
    const int h = blockIdx.y;
    const int b = bx >> 6;              // 64 tiles per batch
    const int bh = b * 8 + h;
    const int tid = threadIdx.x;
    const int w = tid >> 6, lane = tid & 63, quad = lane >> 4, l16 = lane & 15;
    const size_t row0 = (size_t)bx * 128;

#pragma unroll
    for (int i = 0; i < 4; ++i) {
        const int cid = tid + i * 256;
        const int r = cid >> 3;
        const int c8 = (cid & 7) * 8;
        *(uint4*)&Qs[r][c8] = *(const uint4*)&Q[(row0 + r) * 512 + h * 64 + c8];
    }
    if (tid < 64) ksl[tid] = Ksum[bh * 64 + tid];
    __syncthreads();

    if (tid < 128) {                    // reciprocal normalizer per row
        float a = 1e-6f;
#pragma unroll
        for (int d = 0; d < 64; ++d) a += bf2f(Qs[tid][d]) * ksl[d];
        rden[tid] = 1.0f / fmaxf(a, 1e-9f);
    }

    v8bf bfr[2][4];
#pragma unroll
    for (int ksi = 0; ksi < 2; ++ksi)
#pragma unroll
        for (int nb = 0; nb < 4; ++nb)
            bfr[ksi][nb] = *(const v8bf*)
                &KVb[((size_t)bh * 512 + ksi * 256 + nb * 64 + lane) * 8];
    __syncthreads();                    // also publishes rden

    v4f acc[2][4];
#pragma unroll
    for (int i = 0; i < 2; ++i)
#pragma unroll
        for (int j = 0; j < 4; ++j) acc[i][j] = (v4f){0.f, 0.f, 0.f, 0.f};

#pragma unroll
    for (int ksi = 0; ksi < 2; ++ksi) {
        v8bf af[2];
#pragma unroll
        for (int mt = 0; mt < 2; ++mt)
            af[mt] = *(const v8bf*)&Qs[w * 32 + mt * 16 + l16][ksi * 32 + quad * 8];
#pragma unroll
        for (int mt = 0; mt < 2; ++mt)
#pragma unroll
            for (int nb = 0; nb < 4; ++nb)
                acc[mt][nb] = __builtin_amdgcn_mfma_f32_16x16x32_bf16(
                    af[mt], bfr[ksi][nb], acc[mt][nb], 0, 0, 0);
    }

#pragma unroll
    for (int mt = 0; mt < 2; ++mt)
#pragma unroll
        for (int nb = 0; nb < 4; ++nb)
#pragma unroll
            for (int r = 0; r < 4; ++r) {
                const int rl = w * 32 + mt * 16 + quad * 4 + r;
                const int e = nb * 16 + l16;
                const float v = acc[mt][nb][r] * rden[rl];
                Q[(row0 + rl) * 512 + h * 64 + e] = f2bf(v);
            }
}

// ---------------------------------------------------------------------------
extern "C" void kernel_launch(void* const* d_in, const int* in_sizes, int n_in,
                              void* d_out, int out_size, void* d_ws, size_t ws_size,
                              hipStream_t stream) {
    (void)in_sizes; (void)n_in; (void)out_size; (void)ws_size;
    const u16t*  x16  = (const u16t*) d_in[0];
    const float* x32  = (const float*)d_in[0];
    const u16t*  Wq16 = (const u16t*) d_in[1];
    const float* Wq32 = (const float*)d_in[1];
    const u16t*  bq16 = (const u16t*) d_in[2];
    const float* bq32 = (const float*)d_in[2];
    const u16t*  Wk16 = (const u16t*) d_in[3];
    const float* Wk32 = (const float*)d_in[3];
    const u16t*  bk16 = (const u16t*) d_in[4];
    const float* bk32 = (const float*)d_in[4];
    const u16t*  Wv16 = (const u16t*) d_in[5];
    const float* Wv32 = (const float*)d_in[5];
    const u16t*  bv16 = (const u16t*) d_in[6];
    const float* bv32 = (const float*)d_in[6];
    const u16t*  Wo16 = (const u16t*) d_in[7];
    const float* Wo32 = (const float*)d_in[7];
    const u16t*  bo16 = (const u16t*) d_in[8];
    const float* bo32 = (const float*)d_in[8];

    char* ws = (char*)d_ws;
    const size_t SZ  = (size_t)65536 * 512 * sizeof(u16t);     // 64 MiB each
    const size_t KVB = (size_t)64 * 64 * 64 * 4;               // 1 MiB
    const size_t KSB = (size_t)64 * 64 * 4;                    // 16 KiB
    const size_t KVbB = (size_t)64 * 512 * 8 * 2;              // 512 KiB
    u16t*  Qb   = (u16t*)(ws);
    u16t*  Kb   = (u16t*)(ws + SZ);
    u16t*  Vb   = (u16t*)d_out;        // scratch until the final gemm
    float* KV   = (float*)(ws + 2 * SZ);
    float* Ks   = (float*)(ws + 2 * SZ + KVB);
    u16t*  KVb  = (u16t*)(ws + 2 * SZ + KVB + KSB);
    int*   flag = (int*)  (ws + 2 * SZ + KVB + KSB + KVbB);

    hipMemsetAsync(KV, 0, KVB + KSB, stream);
    hipMemsetAsync(flag, 0, sizeof(int), stream);

    const dim3 blk(256);
    dtype_probe<<<dim3(1), blk, 0, stream>>>(x16, flag);
    gemm_nt<true,  true,  false><<<dim3(512, 4), blk, 0, stream>>>(
        x16, x32, Wq16, Wq32, bq16, bq32, Qb, nullptr, flag, 512, 512);
    gemm_nt<true,  true,  false><<<dim3(512, 4), blk, 0, stream>>>(
        x16, x32, Wk16, Wk32, bk16, bk32, Kb, nullptr, flag, 512, 512);
    gemm_nt<false, true,  false><<<dim3(512, 4), blk, 0, stream>>>(
        x16, x32, Wv16, Wv32, bv16, bv32, Vb, nullptr, flag, 512, 512);
    kv_reduce <<<dim3(64, 8), blk, 0, stream>>>(Kb, Vb, KV, Ks);
    kv_pack   <<<dim3(64),    blk, 0, stream>>>(KV, KVb);
    attn_apply<<<dim3(512, 8), blk, 0, stream>>>(Qb, KVb, Ks);
    gemm_nt<false, false, true ><<<dim3(512, 4), blk, 0, stream>>>(
        Qb, nullptr, Wo16, Wo32, bo16, bo32, (u16t*)d_out, (float*)d_out,
        flag, 512, 512);
}

// Round 4
// 596.576 us; speedup vs baseline: 1.5628x; 1.5628x over previous
//
#include <hip/hip_runtime.h>
#include <hip/hip_bf16.h>

// EfficientLinearAttention on MI355X (gfx950).
// B=8 T=8192 C=512 H=8 D=64.  M = B*T = 65536 rows.
// External tensors fp32 (confirmed R3), internal compute bf16, output fp32.
//
// Pipeline:
//   memset KV/Ksum
//   cvt_x    : x fp32 -> bf16 xb            (in d_out[0:64MiB))
//   cvt_wb   : Wq/Wk/Wv/Wo + biases -> bf16 Wpack/bpack (ws)
//   qkv_gemm : fused Q/K/V projection, global_load_lds staging
//              Q=elu(x@Wq^T+bq)+1 -> ws.Qb; K likewise -> ws.Kb; V -> d_out[64MiB:)
//   kv_reduce: KV[bh] += K^T V (MFMA, 8 T-chunks, fp32 atomics); Ksum folded in
//   kv_pack  : KV fp32 -> bf16 in MFMA B-fragment order
//   attn_apply: attn = (Q@KV)/(Q.Ksum+1e-6), in-place on ws.Qb
//   out_gemm : out = attn@Wo^T+bo -> d_out fp32
//
// ws: Qb 64M + Kb 64M + KV 1M + Ks 16K + KVb 512K + Wpack 2M + bpack 4K ~= 131.5 MiB.

typedef unsigned short u16t;
typedef unsigned int   u32t;
typedef __bf16 v8bf __attribute__((ext_vector_type(8)));
typedef u16t   v8u  __attribute__((ext_vector_type(8)));
typedef float  v4f  __attribute__((ext_vector_type(4)));

static __device__ __forceinline__ float bf2f(u16t b) {
    u32t u = ((u32t)b) << 16;
    return __builtin_bit_cast(float, u);
}
static __device__ __forceinline__ u16t f2bf(float f) {
    u32t u = __builtin_bit_cast(u32t, f);
    u += 0x7fffu + ((u >> 16) & 1u);   // round-to-nearest-even
    return (u16t)(u >> 16);
}
static __device__ __forceinline__ v8u cvt8(const float* p) {
    const float4 a = *(const float4*)p;
    const float4 b = *(const float4*)(p + 4);
    v8u r;
    r[0] = f2bf(a.x); r[1] = f2bf(a.y); r[2] = f2bf(a.z); r[3] = f2bf(a.w);
    r[4] = f2bf(b.x); r[5] = f2bf(b.y); r[6] = f2bf(b.z); r[7] = f2bf(b.w);
    return r;
}

// async global->LDS, 16B per lane; LDS dest must be base+lane*16 contiguous.
#define GLDS16(g, l) __builtin_amdgcn_global_load_lds(                       \
        (const __attribute__((address_space(1))) void*)(g),                  \
        (__attribute__((address_space(3))) void*)(l), 16, 0, 0)

// ---------------------------------------------------------------------------
__global__ __launch_bounds__(256) void cvt_x(
        const float* __restrict__ src, u16t* __restrict__ dst) {
    const int i = (blockIdx.x * 256 + threadIdx.x) * 8;   // 16384 blocks
    *(v8u*)&dst[i] = cvt8(&src[i]);
}

__global__ __launch_bounds__(256) void cvt_wb(
        const float* __restrict__ Wq, const float* __restrict__ Wk,
        const float* __restrict__ Wv, const float* __restrict__ Wo,
        const float* __restrict__ bq, const float* __restrict__ bk,
        const float* __restrict__ bv, const float* __restrict__ bo,
        u16t* __restrict__ Wpack, u16t* __restrict__ bpack) {
    const int b = blockIdx.x;
    if (b < 512) {                       // 4 x 512x512 weights, 2048 elems/blk
        const int gidx = (b * 256 + threadIdx.x) * 8;     // [0, 1048576)
        const int seg = gidx >> 18;
        const int off = gidx & 262143;
        const float* src = (seg == 0) ? Wq : (seg == 1) ? Wk
                          : (seg == 2) ? Wv : Wo;
        *(v8u*)&Wpack[gidx] = cvt8(&src[off]);
    } else {                             // 4 biases of 512
        const int seg = b - 512;
        const float* src = (seg == 0) ? bq : (seg == 1) ? bk
                          : (seg == 2) ? bv : bo;
        if (threadIdx.x < 64) {
            const int off = threadIdx.x * 8;
            *(v8u*)&bpack[seg * 512 + off] = cvt8(&src[off]);
        }
    }
}

// ---------------------------------------------------------------------------
// Shared GEMM core: C_tile[128x128] = A[128xK] @ W[128xK]^T, K=512, bf16,
// fp32 accum.  4 waves in 2x2 grid, 64x64 per wave, 4x4 16x16x32 MFMA tiles.
// Staging via global_load_lds dwordx4: per wave 2 A-issues + 2 B-issues of
// 64 lanes x 16B = 1KiB each; LDS As/Bs row-major [128][32] (contiguous as
// the DMA requires; fragment b128 reads sit at the 8-access/bank floor).
// ---------------------------------------------------------------------------
static __device__ __forceinline__ void gemm_core(
        const u16t* __restrict__ A, const u16t* __restrict__ W,
        size_t mbase, int nbase, u16t (*As)[32], u16t (*Bs)[32],
        v4f acc[4][4], int tid) {
    const int w    = tid >> 6;
    const int lane = tid & 63;
    const int quad = lane >> 4;
    const int l16  = lane & 15;
    const int wm   = (w & 1) * 64;
    const int wn   = (w >> 1) * 64;

#pragma unroll
    for (int i = 0; i < 4; ++i)
#pragma unroll
        for (int j = 0; j < 4; ++j) acc[i][j] = (v4f){0.f, 0.f, 0.f, 0.f};

    // DMA source/dest for this thread's two A-issues and two B-issues
    const int r0 = (w * 2 + 0) * 16 + (lane >> 2);
    const int r1 = (w * 2 + 1) * 16 + (lane >> 2);
    const int c8 = (lane & 3) * 8;
    const u16t* pa0 = A + (mbase + r0) * 512 + c8;
    const u16t* pa1 = A + (mbase + r1) * 512 + c8;
    const u16t* pb0 = W + (size_t)(nbase + r0) * 512 + c8;
    const u16t* pb1 = W + (size_t)(nbase + r1) * 512 + c8;
    u16t* la0 = &As[0][0] + (w * 2 + 0) * 512 + lane * 8;
    u16t* la1 = &As[0][0] + (w * 2 + 1) * 512 + lane * 8;
    u16t* lb0 = &Bs[0][0] + (w * 2 + 0) * 512 + lane * 8;
    u16t* lb1 = &Bs[0][0] + (w * 2 + 1) * 512 + lane * 8;

    for (int kt = 0; kt < 16; ++kt) {
        GLDS16(pa0, la0); GLDS16(pa1, la1);
        GLDS16(pb0, lb0); GLDS16(pb1, lb1);
        pa0 += 32; pa1 += 32; pb0 += 32; pb1 += 32;
        __syncthreads();                 // drains vmcnt: DMA landed

        v8bf af[4], bfr[4];
#pragma unroll
        for (int mi = 0; mi < 4; ++mi)
            af[mi] = *(const v8bf*)&As[wm + mi * 16 + l16][quad * 8];
#pragma unroll
        for (int ni = 0; ni < 4; ++ni)
            bfr[ni] = *(const v8bf*)&Bs[wn + ni * 16 + l16][quad * 8];
#pragma unroll
        for (int mi = 0; mi < 4; ++mi)
#pragma unroll
            for (int ni = 0; ni < 4; ++ni)
                acc[mi][ni] = __builtin_amdgcn_mfma_f32_16x16x32_bf16(
                    af[mi], bfr[ni], acc[mi][ni], 0, 0, 0);
        __syncthreads();                 // LDS consumed, safe to overwrite
    }
}

// Fused Q/K/V projection.  grid (12, 512): x = p*4 + n-tile (p: 0=Q 1=K 2=V),
// y = m-tile (y-fast dispatch -> 12 consecutive blocks share one A-tile in L2).
__global__ __launch_bounds__(256) void qkv_gemm(
        const u16t* __restrict__ xb, const u16t* __restrict__ Wpack,
        const u16t* __restrict__ bpack,
        u16t* __restrict__ Qb, u16t* __restrict__ Kb, u16t* __restrict__ Vb) {
    __shared__ u16t As[128][32];
    __shared__ u16t Bs[128][32];
    const int p = blockIdx.x >> 2;
    const int nbase = (blockIdx.x & 3) * 128;
    const size_t mbase = (size_t)blockIdx.y * 128;
    const u16t* W = Wpack + (size_t)p * 262144;
    const u16t* bias = bpack + p * 512;
    u16t* C = (p == 0) ? Qb : (p == 1) ? Kb : Vb;
    const bool elu = (p < 2);
    const int tid = threadIdx.x;
    const int w = tid >> 6, lane = tid & 63, quad = lane >> 4, l16 = lane & 15;
    const int wm = (w & 1) * 64, wn = (w >> 1) * 64;

    v4f acc[4][4];
    gemm_core(xb, W, mbase, nbase, As, Bs, acc, tid);

#pragma unroll
    for (int ni = 0; ni < 4; ++ni) {
        const int col = nbase + wn + ni * 16 + l16;
        const float bb = bf2f(bias[col]);
#pragma unroll
        for (int mi = 0; mi < 4; ++mi)
#pragma unroll
            for (int r = 0; r < 4; ++r) {
                const size_t row = mbase + wm + mi * 16 + quad * 4 + r;
                float v = acc[mi][ni][r] + bb;
                if (elu) v = (v > 0.f) ? (v + 1.f) : __expf(v);   // elu(x)+1
                C[row * 512 + col] = f2bf(v);
            }
    }
}

// out = attn @ Wo^T + bo, fp32 out.  grid (4, 512).
__global__ __launch_bounds__(256) void out_gemm(
        const u16t* __restrict__ attn, const u16t* __restrict__ Wo,
        const u16t* __restrict__ bo, float* __restrict__ C) {
    __shared__ u16t As[128][32];
    __shared__ u16t Bs[128][32];
    const int nbase = blockIdx.x * 128;
    const size_t mbase = (size_t)blockIdx.y * 128;
    const int tid = threadIdx.x;
    const int w = tid >> 6, lane = tid & 63, quad = lane >> 4, l16 = lane & 15;
    const int wm = (w & 1) * 64, wn = (w >> 1) * 64;

    v4f acc[4][4];
    gemm_core(attn, Wo, mbase, nbase, As, Bs, acc, tid);

#pragma unroll
    for (int ni = 0; ni < 4; ++ni) {
        const int col = nbase + wn + ni * 16 + l16;
        const float bb = bf2f(bo[col]);
#pragma unroll
        for (int mi = 0; mi < 4; ++mi)
#pragma unroll
            for (int r = 0; r < 4; ++r) {
                const size_t row = mbase + wm + mi * 16 + quad * 4 + r;
                C[row * 512 + col] = acc[mi][ni][r] + bb;
            }
    }
}

// ---------------------------------------------------------------------------
// KV[bh][d][e] = sum_t K[t][d]*V[t][e];  Ksum[bh][d] = sum_t K[t][d].
// grid (64 bh, 8 T-chunks), block 256.  Unchanged from R3 (proven).
// ---------------------------------------------------------------------------
__global__ __launch_bounds__(256) void kv_reduce(
        const u16t* __restrict__ Kp, const u16t* __restrict__ Vp,
        float* __restrict__ KV, float* __restrict__ Ksum) {
    __shared__ u16t Kl[64][66];
    __shared__ u16t Vl[64][66];
    const int bh = blockIdx.x;
    const int chunk = blockIdx.y;
    const int b = bh >> 3, h = bh & 7;
    const int tid = threadIdx.x;
    const int w = tid >> 6, lane = tid & 63, quad = lane >> 4, l16 = lane & 15;
    const int trow0 = tid >> 3;
    const int c8 = (tid & 7) * 8;
    const size_t rowbase = (size_t)b * 8192;

    v4f acc[4];
#pragma unroll
    for (int i = 0; i < 4; ++i) acc[i] = (v4f){0.f, 0.f, 0.f, 0.f};
    float ks[8];
#pragma unroll
    for (int j = 0; j < 8; ++j) ks[j] = 0.f;

    for (int tile = 0; tile < 16; ++tile) {
        const int t0 = chunk * 1024 + tile * 64;
#pragma unroll
        for (int i = 0; i < 2; ++i) {
            const int trow = trow0 + i * 32;
            const size_t goff = (rowbase + t0 + trow) * 512 + h * 64 + c8;
            const uint4 kq = *(const uint4*)&Kp[goff];
            const uint4 vq = *(const uint4*)&Vp[goff];
            *(u32t*)&Kl[trow][c8 + 0] = kq.x;
            *(u32t*)&Kl[trow][c8 + 2] = kq.y;
            *(u32t*)&Kl[trow][c8 + 4] = kq.z;
            *(u32t*)&Kl[trow][c8 + 6] = kq.w;
            *(u32t*)&Vl[trow][c8 + 0] = vq.x;
            *(u32t*)&Vl[trow][c8 + 2] = vq.y;
            *(u32t*)&Vl[trow][c8 + 4] = vq.z;
            *(u32t*)&Vl[trow][c8 + 6] = vq.w;
            const v8u ku = __builtin_bit_cast(v8u, kq);
#pragma unroll
            for (int j = 0; j < 8; ++j) ks[j] += bf2f(ku[j]);
        }
        __syncthreads();
#pragma unroll
        for (int ts = 0; ts < 2; ++ts) {
            v8u au;
#pragma unroll
            for (int j = 0; j < 8; ++j)
                au[j] = Kl[ts * 32 + quad * 8 + j][w * 16 + l16];
            const v8bf af = __builtin_bit_cast(v8bf, au);
#pragma unroll
            for (int et = 0; et < 4; ++et) {
                v8u bu;
#pragma unroll
                for (int j = 0; j < 8; ++j)
                    bu[j] = Vl[ts * 32 + quad * 8 + j][et * 16 + l16];
                acc[et] = __builtin_amdgcn_mfma_f32_16x16x32_bf16(
                    af, __builtin_bit_cast(v8bf, bu), acc[et], 0, 0, 0);
            }
        }
        __syncthreads();
    }

#pragma unroll
    for (int et = 0; et < 4; ++et)
#pragma unroll
        for (int r = 0; r < 4; ++r) {
            const int d = w * 16 + quad * 4 + r;
            const int e = et * 16 + l16;
            atomicAdd(&KV[((size_t)bh * 64 + d) * 64 + e], acc[et][r]);
        }
#pragma unroll
    for (int j = 0; j < 8; ++j)
        atomicAdd(&Ksum[bh * 64 + c8 + j], ks[j]);
}

// fp32 KV[bh][64][64] -> bf16 in MFMA B-fragment order.
__global__ __launch_bounds__(256) void kv_pack(
        const float* __restrict__ KV, u16t* __restrict__ KVb) {
    const int bh = blockIdx.x;
    const int tid = threadIdx.x;
#pragma unroll
    for (int i = 0; i < 2; ++i) {
        const int c = tid + i * 256;
        const int ksi = c >> 8;
        const int nb = (c >> 6) & 3;
        const int L = c & 63;
        const int quad = L >> 4, l16 = L & 15;
        v8u pk;
#pragma unroll
        for (int j = 0; j < 8; ++j) {
            const int d = ksi * 32 + quad * 8 + j;
            const int e = nb * 16 + l16;
            pk[j] = f2bf(KV[((size_t)bh * 64 + d) * 64 + e]);
        }
        *(v8u*)&KVb[((size_t)bh * 512 + c) * 8] = pk;
    }
}

// attn = (Q @ KV) / (Q.Ksum + 1e-6), in-place over Q.  grid (512, 8).
__global__ __launch_bounds__(256) void attn_apply(
        u16t* __restrict__ Q, const u16t* __restrict__ KVb,
        const float* __restrict__ Ksum) {
    __shared__ u16t Qs[128][72];
    __shared__ float ksl[64];
    __shared__ float rden[128];
    const int bx = blockIdx.x;
    const int h = blockIdx.y;
    const int b = bx >> 6;
    const int bh = b * 8 + h;
    const int tid = threadIdx.x;
    const int w = tid >> 6, lane = tid & 63, quad = lane >> 4, l16 = lane & 15;
    const size_t row0 = (size_t)bx * 128;

#pragma unroll
    for (int i = 0; i < 4; ++i) {
        const int cid = tid + i * 256;
        const int r = cid >> 3;
        const int c8 = (cid & 7) * 8;
        *(uint4*)&Qs[r][c8] = *(const uint4*)&Q[(row0 + r) * 512 + h * 64 + c8];
    }
    if (tid < 64) ksl[tid] = Ksum[bh * 64 + tid];
    __syncthreads();

    if (tid < 128) {
        float a = 1e-6f;
#pragma unroll
        for (int d = 0; d < 64; ++d) a += bf2f(Qs[tid][d]) * ksl[d];
        rden[tid] = 1.0f / fmaxf(a, 1e-9f);
    }

    v8bf bfr[2][4];
#pragma unroll
    for (int ksi = 0; ksi < 2; ++ksi)
#pragma unroll
        for (int nb = 0; nb < 4; ++nb)
            bfr[ksi][nb] = *(const v8bf*)
                &KVb[((size_t)bh * 512 + ksi * 256 + nb * 64 + lane) * 8];
    __syncthreads();

    v4f acc[2][4];
#pragma unroll
    for (int i = 0; i < 2; ++i)
#pragma unroll
        for (int j = 0; j < 4; ++j) acc[i][j] = (v4f){0.f, 0.f, 0.f, 0.f};

#pragma unroll
    for (int ksi = 0; ksi < 2; ++ksi) {
        v8bf af[2];
#pragma unroll
        for (int mt = 0; mt < 2; ++mt)
            af[mt] = *(const v8bf*)&Qs[w * 32 + mt * 16 + l16][ksi * 32 + quad * 8];
#pragma unroll
        for (int mt = 0; mt < 2; ++mt)
#pragma unroll
            for (int nb = 0; nb < 4; ++nb)
                acc[mt][nb] = __builtin_amdgcn_mfma_f32_16x16x32_bf16(
                    af[mt], bfr[ksi][nb], acc[mt][nb], 0, 0, 0);
    }

#pragma unroll
    for (int mt = 0; mt < 2; ++mt)
#pragma unroll
        for (int nb = 0; nb < 4; ++nb)
#pragma unroll
            for (int r = 0; r < 4; ++r) {
                const int rl = w * 32 + mt * 16 + quad * 4 + r;
                const int e = nb * 16 + l16;
                const float v = acc[mt][nb][r] * rden[rl];
                Q[(row0 + rl) * 512 + h * 64 + e] = f2bf(v);
            }
}

// ---------------------------------------------------------------------------
extern "C" void kernel_launch(void* const* d_in, const int* in_sizes, int n_in,
                              void* d_out, int out_size, void* d_ws, size_t ws_size,
                              hipStream_t stream) {
    (void)in_sizes; (void)n_in; (void)out_size; (void)ws_size;
    const float* x32  = (const float*)d_in[0];
    const float* Wq32 = (const float*)d_in[1];
    const float* bq32 = (const float*)d_in[2];
    const float* Wk32 = (const float*)d_in[3];
    const float* bk32 = (const float*)d_in[4];
    const float* Wv32 = (const float*)d_in[5];
    const float* bv32 = (const float*)d_in[6];
    const float* Wo32 = (const float*)d_in[7];
    const float* bo32 = (const float*)d_in[8];

    // d_out (128 MiB fp32) doubles as scratch: xb bf16 + Vb bf16.
    u16t* xb = (u16t*)d_out;
    u16t* Vb = (u16t*)d_out + (size_t)33554432;

    char* ws = (char*)d_ws;
    const size_t SZ   = (size_t)65536 * 512 * sizeof(u16t);    // 64 MiB
    const size_t KVB  = (size_t)64 * 64 * 64 * 4;              // 1 MiB
    const size_t KSB  = (size_t)64 * 64 * 4;                   // 16 KiB
    const size_t KVbB = (size_t)64 * 512 * 16;                 // 512 KiB
    u16t*  Qb    = (u16t*)(ws);
    u16t*  Kb    = (u16t*)(ws + SZ);
    float* KV    = (float*)(ws + 2 * SZ);
    float* Ks    = (float*)(ws + 2 * SZ + KVB);
    u16t*  KVb   = (u16t*)(ws + 2 * SZ + KVB + KSB);
    u16t*  Wpack = (u16t*)(ws + 2 * SZ + KVB + KSB + KVbB);
    u16t*  bpack = Wpack + (size_t)4 * 262144;

    hipMemsetAsync(KV, 0, KVB + KSB, stream);

    const dim3 blk(256);
    cvt_x <<<dim3(16384), blk, 0, stream>>>(x32, xb);
    cvt_wb<<<dim3(516),   blk, 0, stream>>>(Wq32, Wk32, Wv32, Wo32,
                                            bq32, bk32, bv32, bo32,
                                            Wpack, bpack);
    qkv_gemm  <<<dim3(12, 512), blk, 0, stream>>>(xb, Wpack, bpack, Qb, Kb, Vb);
    kv_reduce <<<dim3(64, 8),   blk, 0, stream>>>(Kb, Vb, KV, Ks);
    kv_pack   <<<dim3(64),      blk, 0, stream>>>(KV, KVb);
    attn_apply<<<dim3(512, 8),  blk, 0, stream>>>(Qb, KVb, Ks);
    out_gemm  <<<dim3(4, 512),  blk, 0, stream>>>(Qb, Wpack + 3 * 262144,
                                                  bpack + 3 * 512,
                                                  (float*)d_out);
}